// Round 1
// baseline (1023.191 us; speedup 1.0000x reference)
//
#include <hip/hip_runtime.h>

#define FEAT 48
#define CH 12           // float4 chunks per node row (48 f32 = 12 float4)
#define STEPS 10
constexpr float LAM   = 0.9f;
constexpr float OMLAM = 0.1f;   // float(1.0 - 0.9)

// --- setup kernels -------------------------------------------------------

// in-degree (by col) and out-count (by row) in one pass
__global__ void count_kernel(const int* __restrict__ row, const int* __restrict__ col,
                             int* __restrict__ deg, int* __restrict__ cnt, int E) {
    int e = blockIdx.x * blockDim.x + threadIdx.x;
    if (e < E) {
        atomicAdd(&deg[col[e]], 1);
        atomicAdd(&cnt[row[e]], 1);
    }
}

// numpy G[mask]=Y last-write-wins: highest i wins per node
__global__ void winner_kernel(const int* __restrict__ mask, int* __restrict__ winner, int M) {
    int i = blockIdx.x * blockDim.x + threadIdx.x;
    if (i < M) atomicMax(&winner[mask[i]], i);
}

__global__ void dinv_kernel(const int* __restrict__ deg, float* __restrict__ dinv, int N) {
    int v = blockIdx.x * blockDim.x + threadIdx.x;
    if (v < N) dinv[v] = (float)(1.0 / sqrt((double)deg[v]));   // deg >= 1 guaranteed
}

// single-block exclusive scan of cnt[0..n) -> off[0..n]
__global__ void scan_kernel(const int* __restrict__ cnt, int* __restrict__ off, int n) {
    __shared__ int part[1024];
    int tid = threadIdx.x;
    int chunk = (n + 1023) >> 10;
    int start = min(tid * chunk, n);
    int end   = min(start + chunk, n);
    int s = 0;
    for (int i = start; i < end; ++i) s += cnt[i];
    part[tid] = s;
    __syncthreads();
    for (int d = 1; d < 1024; d <<= 1) {
        int v = (tid >= d) ? part[tid - d] : 0;
        __syncthreads();
        part[tid] += v;
        __syncthreads();
    }
    int run = (tid == 0) ? 0 : part[tid - 1];
    for (int i = start; i < end; ++i) { off[i] = run; run += cnt[i]; }
    if (tid == 1023) off[n] = part[1023];
}

__global__ void fill_kernel(const int* __restrict__ row, const int* __restrict__ col,
                            const int* __restrict__ off, int* __restrict__ cursor,
                            const float* __restrict__ dinv,
                            int* __restrict__ csr_col, float* __restrict__ csr_w, int E) {
    int e = blockIdx.x * blockDim.x + threadIdx.x;
    if (e < E) {
        int r = row[e], c = col[e];
        int p = atomicAdd(&cursor[r], 1);
        int idx = off[r] + p;
        csr_col[idx] = c;
        csr_w[idx]   = dinv[r] * dinv[c];
    }
}

__global__ void apply_y_kernel(const float4* __restrict__ Y4, const int* __restrict__ mask,
                               const int* __restrict__ winner, float4* __restrict__ G4, int M) {
    int t = blockIdx.x * blockDim.x + threadIdx.x;
    if (t < M * CH) {
        int i = t / CH, ck = t % CH;
        int node = mask[i];
        if (winner[node] == i) G4[(size_t)node * CH + ck] = Y4[(size_t)i * CH + ck];
    }
}

// --- diffusion step: out[r] = LAM * sum_j w_j * x[col_j] + (1-LAM)*G[r] ---
// 12 consecutive lanes handle one row (one float4 chunk each) -> each
// neighbor gather is a coalesced 192B read of x[c].
__global__ void diffuse_kernel(const float4* __restrict__ x4, const float4* __restrict__ G4,
                               const int* __restrict__ off, const int* __restrict__ csr_col,
                               const float* __restrict__ csr_w,
                               float4* __restrict__ out4, int N) {
    int t = blockIdx.x * blockDim.x + threadIdx.x;
    if (t >= N * CH) return;
    int r = t / CH, ck = t - r * CH;
    int j0 = off[r], j1 = off[r + 1];
    float4 acc = make_float4(0.f, 0.f, 0.f, 0.f);
    for (int j = j0; j < j1; ++j) {
        int   c = csr_col[j];
        float w = csr_w[j];
        float4 xv = x4[(size_t)c * CH + ck];
        acc.x = fmaf(w, xv.x, acc.x);
        acc.y = fmaf(w, xv.y, acc.y);
        acc.z = fmaf(w, xv.z, acc.z);
        acc.w = fmaf(w, xv.w, acc.w);
    }
    float4 g = G4[t];
    float4 o;
    o.x = fmaf(LAM, acc.x, OMLAM * g.x);
    o.y = fmaf(LAM, acc.y, OMLAM * g.y);
    o.z = fmaf(LAM, acc.z, OMLAM * g.z);
    o.w = fmaf(LAM, acc.w, OMLAM * g.w);
    out4[t] = o;
}

// --- launch --------------------------------------------------------------

extern "C" void kernel_launch(void* const* d_in, const int* in_sizes, int n_in,
                              void* d_out, int out_size, void* d_ws, size_t ws_size,
                              hipStream_t stream) {
    const float* Z    = (const float*)d_in[0];
    const float* Y    = (const float*)d_in[1];
    const int*   mask = (const int*)d_in[2];
    const int*   ei   = (const int*)d_in[3];
    // d_in[4] = beta, unused (noise=False branch)

    const int N = in_sizes[0] / FEAT;
    const int M = in_sizes[2];
    const int E = in_sizes[3] / 2;
    const int* row = ei;
    const int* col = ei + E;

    char* ws = (char*)d_ws;
    size_t pos = 0;
    auto alloc = [&](size_t bytes) -> void* {
        void* p = ws + pos;
        pos = (pos + bytes + 255) & ~(size_t)255;
        return p;
    };
    float* G       = (float*)alloc((size_t)N * FEAT * 4);
    float* XA      = (float*)alloc((size_t)N * FEAT * 4);
    int*   deg     = (int*)  alloc((size_t)N * 4);
    float* dinv    = (float*)alloc((size_t)N * 4);
    int*   cnt     = (int*)  alloc((size_t)N * 4);
    int*   off     = (int*)  alloc((size_t)(N + 1) * 4);
    int*   cursor  = (int*)  alloc((size_t)N * 4);
    int*   winner  = (int*)  alloc((size_t)N * 4);
    int*   csr_col = (int*)  alloc((size_t)E * 4);
    float* csr_w   = (float*)alloc((size_t)E * 4);

    hipMemsetAsync(deg,    0,    (size_t)N * 4, stream);
    hipMemsetAsync(cnt,    0,    (size_t)N * 4, stream);
    hipMemsetAsync(cursor, 0,    (size_t)N * 4, stream);
    hipMemsetAsync(winner, 0xFF, (size_t)N * 4, stream);

    const int B = 256;
    count_kernel <<<(E + B - 1) / B, B, 0, stream>>>(row, col, deg, cnt, E);
    winner_kernel<<<(M + B - 1) / B, B, 0, stream>>>(mask, winner, M);
    dinv_kernel  <<<(N + B - 1) / B, B, 0, stream>>>(deg, dinv, N);
    scan_kernel  <<<1, 1024, 0, stream>>>(cnt, off, N);
    fill_kernel  <<<(E + B - 1) / B, B, 0, stream>>>(row, col, off, cursor, dinv, csr_col, csr_w, E);

    hipMemcpyAsync(G, Z, (size_t)N * FEAT * 4, hipMemcpyDeviceToDevice, stream);
    apply_y_kernel<<<(M * CH + B - 1) / B, B, 0, stream>>>((const float4*)Y, mask, winner, (float4*)G, M);

    // 10 diffusion steps; ping-pong XA <-> d_out so step 9 lands in d_out
    float4* bufs[2] = { (float4*)XA, (float4*)d_out };
    const float4* src = (const float4*)G;
    const int nt = N * CH;
    for (int it = 0; it < STEPS; ++it) {
        float4* dst = bufs[it & 1];
        diffuse_kernel<<<(nt + B - 1) / B, B, 0, stream>>>(
            src, (const float4*)G, off, csr_col, csr_w, dst, N);
        src = dst;
    }
}

// Round 2
// 849.038 us; speedup vs baseline: 1.2051x; 1.2051x over previous
//
#include <hip/hip_runtime.h>

#define FEAT 48
#define CH 12           // float4 chunks per node row (48 f32 = 12 float4)
#define STEPS 10
constexpr float LAM   = 0.9f;
constexpr float OMLAM = 0.1f;

#define SCB 1024        // scan block threads
#define SCE 4           // elems per scan thread (block covers 4096)

// --- setup kernels -------------------------------------------------------

// in-degree (by col), out-count (by row) + per-edge slot, fused winner pass
__global__ void count_kernel(const int* __restrict__ row, const int* __restrict__ col,
                             int* __restrict__ deg, int* __restrict__ cnt,
                             int* __restrict__ slot,
                             const int* __restrict__ mask, int* __restrict__ winner,
                             int E, int M) {
    int e = blockIdx.x * blockDim.x + threadIdx.x;
    if (e < E) {
        atomicAdd(&deg[col[e]], 1);
        slot[e] = atomicAdd(&cnt[row[e]], 1);
    }
    if (e < M) atomicMax(&winner[mask[e]], e);   // numpy last-write-wins
}

__global__ void dinv_kernel(const int* __restrict__ deg, float* __restrict__ dinv, int N) {
    int v = blockIdx.x * blockDim.x + threadIdx.x;
    if (v < N) dinv[v] = (float)(1.0 / sqrt((double)deg[v]));   // deg >= 1 guaranteed
}

// hierarchical exclusive scan: part 1 — per-block scan + block sums
__global__ void scan_part(const int* __restrict__ cnt, int* __restrict__ off,
                          int* __restrict__ bsum, int n) {
    __shared__ int part[SCB];
    int tid  = threadIdx.x;
    int base = blockIdx.x * (SCB * SCE) + tid * SCE;
    int v[SCE];
    int s = 0;
    #pragma unroll
    for (int k = 0; k < SCE; ++k) {
        int i = base + k;
        v[k] = (i < n) ? cnt[i] : 0;
        s += v[k];
    }
    part[tid] = s;
    __syncthreads();
    for (int d = 1; d < SCB; d <<= 1) {
        int t = (tid >= d) ? part[tid - d] : 0;
        __syncthreads();
        part[tid] += t;
        __syncthreads();
    }
    int run = (tid ? part[tid - 1] : 0);
    #pragma unroll
    for (int k = 0; k < SCE; ++k) {
        int i = base + k;
        if (i < n) off[i] = run;
        run += v[k];
    }
    if (tid == SCB - 1) bsum[blockIdx.x] = part[SCB - 1];
}

// part 2 — add block-prefix; block 0 thread 0 also writes off[n] = total
__global__ void scan_fixup(int* __restrict__ off, const int* __restrict__ bsum,
                           int nblocks, int n) {
    __shared__ int addv;
    int tid = threadIdx.x;
    if (tid == 0) {
        int s = 0;
        for (int b = 0; b < (int)blockIdx.x; ++b) s += bsum[b];
        addv = s;
        if (blockIdx.x == 0) {
            int tot = 0;
            for (int b = 0; b < nblocks; ++b) tot += bsum[b];
            off[n] = tot;
        }
    }
    __syncthreads();
    if (blockIdx.x == 0) return;              // adds 0
    int base = blockIdx.x * (SCB * SCE) + tid * SCE;
    #pragma unroll
    for (int k = 0; k < SCE; ++k) {
        int i = base + k;
        if (i < n) off[i] += addv;
    }
}

// atomic-free CSR fill using precomputed slots; packs (col, w) into int2
__global__ void fill_kernel(const int* __restrict__ row, const int* __restrict__ col,
                            const int* __restrict__ off, const int* __restrict__ slot,
                            const float* __restrict__ dinv,
                            int2* __restrict__ csr, int E) {
    int e = blockIdx.x * blockDim.x + threadIdx.x;
    if (e < E) {
        int r = row[e], c = col[e];
        float w = dinv[r] * dinv[c];
        csr[off[r] + slot[e]] = make_int2(c, __float_as_int(w));
    }
}

__global__ void apply_y_kernel(const float4* __restrict__ Y4, const int* __restrict__ mask,
                               const int* __restrict__ winner, float4* __restrict__ G4, int M) {
    int t = blockIdx.x * blockDim.x + threadIdx.x;
    if (t < M * CH) {
        int i = t / CH, ck = t % CH;
        int node = mask[i];
        if (winner[node] == i) G4[(size_t)node * CH + ck] = Y4[(size_t)i * CH + ck];
    }
}

// --- diffusion step: out[r] = LAM * sum_j w_j * x[col_j] + (1-LAM)*G[r] ---
// 12 consecutive lanes handle one row (one float4 chunk each); each neighbor
// gather is a coalesced 192B read of x[c]; CSR metadata is an 8B broadcast.
__global__ void diffuse_kernel(const float4* __restrict__ x4, const float4* __restrict__ G4,
                               const int* __restrict__ off, const int2* __restrict__ csr,
                               float4* __restrict__ out4, int N) {
    int t = blockIdx.x * blockDim.x + threadIdx.x;
    if (t >= N * CH) return;
    int r = t / CH, ck = t - r * CH;
    int j0 = off[r], j1 = off[r + 1];
    float4 acc = make_float4(0.f, 0.f, 0.f, 0.f);
    for (int j = j0; j < j1; ++j) {
        int2  cw = csr[j];
        float w  = __int_as_float(cw.y);
        float4 xv = x4[(size_t)cw.x * CH + ck];
        acc.x = fmaf(w, xv.x, acc.x);
        acc.y = fmaf(w, xv.y, acc.y);
        acc.z = fmaf(w, xv.z, acc.z);
        acc.w = fmaf(w, xv.w, acc.w);
    }
    float4 g = G4[t];
    float4 o;
    o.x = fmaf(LAM, acc.x, OMLAM * g.x);
    o.y = fmaf(LAM, acc.y, OMLAM * g.y);
    o.z = fmaf(LAM, acc.z, OMLAM * g.z);
    o.w = fmaf(LAM, acc.w, OMLAM * g.w);
    out4[t] = o;
}

// --- launch --------------------------------------------------------------

extern "C" void kernel_launch(void* const* d_in, const int* in_sizes, int n_in,
                              void* d_out, int out_size, void* d_ws, size_t ws_size,
                              hipStream_t stream) {
    const float* Z    = (const float*)d_in[0];
    const float* Y    = (const float*)d_in[1];
    const int*   mask = (const int*)d_in[2];
    const int*   ei   = (const int*)d_in[3];

    const int N = in_sizes[0] / FEAT;
    const int M = in_sizes[2];
    const int E = in_sizes[3] / 2;
    const int* row = ei;
    const int* col = ei + E;

    char* ws = (char*)d_ws;
    size_t pos = 0;
    auto alloc = [&](size_t bytes) -> void* {
        void* p = ws + pos;
        pos = (pos + bytes + 255) & ~(size_t)255;
        return p;
    };
    float* G      = (float*)alloc((size_t)N * FEAT * 4);
    float* XA     = (float*)alloc((size_t)N * FEAT * 4);
    int*   deg    = (int*)  alloc((size_t)N * 4);
    float* dinv   = (float*)alloc((size_t)N * 4);
    int*   cnt    = (int*)  alloc((size_t)N * 4);
    int*   off    = (int*)  alloc((size_t)(N + 1) * 4);
    int*   winner = (int*)  alloc((size_t)N * 4);
    int*   slot   = (int*)  alloc((size_t)E * 4);
    int2*  csr    = (int2*) alloc((size_t)E * 8);
    int*   bsum   = (int*)  alloc((size_t)1024 * 4);

    hipMemsetAsync(deg,    0,    (size_t)N * 4, stream);
    hipMemsetAsync(cnt,    0,    (size_t)N * 4, stream);
    hipMemsetAsync(winner, 0xFF, (size_t)N * 4, stream);

    const int B = 256;
    count_kernel<<<(E + B - 1) / B, B, 0, stream>>>(row, col, deg, cnt, slot,
                                                    mask, winner, E, M);
    dinv_kernel <<<(N + B - 1) / B, B, 0, stream>>>(deg, dinv, N);

    const int scan_nb = (N + SCB * SCE - 1) / (SCB * SCE);
    scan_part <<<scan_nb, SCB, 0, stream>>>(cnt, off, bsum, N);
    scan_fixup<<<scan_nb, SCB, 0, stream>>>(off, bsum, scan_nb, N);

    fill_kernel<<<(E + B - 1) / B, B, 0, stream>>>(row, col, off, slot, dinv, csr, E);

    hipMemcpyAsync(G, Z, (size_t)N * FEAT * 4, hipMemcpyDeviceToDevice, stream);
    apply_y_kernel<<<(M * CH + B - 1) / B, B, 0, stream>>>((const float4*)Y, mask, winner,
                                                           (float4*)G, M);

    // 10 diffusion steps; ping-pong XA <-> d_out so step 9 lands in d_out
    float4* bufs[2] = { (float4*)XA, (float4*)d_out };
    const float4* src = (const float4*)G;
    const int nt = N * CH;
    for (int it = 0; it < STEPS; ++it) {
        float4* dst = bufs[it & 1];
        diffuse_kernel<<<(nt + B - 1) / B, B, 0, stream>>>(
            src, (const float4*)G, off, csr, dst, N);
        src = dst;
    }
}

// Round 3
// 613.553 us; speedup vs baseline: 1.6676x; 1.3838x over previous
//
#include <hip/hip_runtime.h>
#include <hip/hip_fp16.h>

#define FEAT 48
#define CH 12           // 12 lanes per node row; f32: float4/lane, fp16: 8B/lane
#define STEPS 10
constexpr float LAM   = 0.9f;
constexpr float OMLAM = 0.1f;

#define SCB 1024        // scan block threads
#define SCE 4           // elems per scan thread

// --- setup kernels -------------------------------------------------------

// in-degree (by col), out-count+slot (by row), winner pass; grid-stride ILP
__global__ void count_kernel(const int* __restrict__ row, const int* __restrict__ col,
                             int* __restrict__ deg, int* __restrict__ cnt,
                             int* __restrict__ slot,
                             const int* __restrict__ mask, int* __restrict__ winner,
                             int E, int M) {
    int t = blockIdx.x * blockDim.x + threadIdx.x;
    int stride = gridDim.x * blockDim.x;
    for (int e = t; e < E; e += stride) {
        atomicAdd(&deg[col[e]], 1);
        slot[e] = atomicAdd(&cnt[row[e]], 1);
    }
    for (int i = t; i < M; i += stride)
        atomicMax(&winner[mask[i]], i);      // numpy last-write-wins
}

__global__ void dinv_kernel(const int* __restrict__ deg, float* __restrict__ dinv, int N) {
    int v = blockIdx.x * blockDim.x + threadIdx.x;
    if (v < N) dinv[v] = (float)(1.0 / sqrt((double)deg[v]));   // deg >= 1
}

// hierarchical exclusive scan
__global__ void scan_part(const int* __restrict__ cnt, int* __restrict__ off,
                          int* __restrict__ bsum, int n) {
    __shared__ int part[SCB];
    int tid  = threadIdx.x;
    int base = blockIdx.x * (SCB * SCE) + tid * SCE;
    int v[SCE];
    int s = 0;
    #pragma unroll
    for (int k = 0; k < SCE; ++k) {
        int i = base + k;
        v[k] = (i < n) ? cnt[i] : 0;
        s += v[k];
    }
    part[tid] = s;
    __syncthreads();
    for (int d = 1; d < SCB; d <<= 1) {
        int tv = (tid >= d) ? part[tid - d] : 0;
        __syncthreads();
        part[tid] += tv;
        __syncthreads();
    }
    int run = (tid ? part[tid - 1] : 0);
    #pragma unroll
    for (int k = 0; k < SCE; ++k) {
        int i = base + k;
        if (i < n) off[i] = run;
        run += v[k];
    }
    if (tid == SCB - 1) bsum[blockIdx.x] = part[SCB - 1];
}

__global__ void scan_fixup(int* __restrict__ off, const int* __restrict__ bsum,
                           int nblocks, int n) {
    __shared__ int addv;
    int tid = threadIdx.x;
    if (tid == 0) {
        int s = 0;
        for (int b = 0; b < (int)blockIdx.x; ++b) s += bsum[b];
        addv = s;
        if (blockIdx.x == 0) {
            int tot = 0;
            for (int b = 0; b < nblocks; ++b) tot += bsum[b];
            off[n] = tot;
        }
    }
    __syncthreads();
    if (blockIdx.x == 0) return;
    int base = blockIdx.x * (SCB * SCE) + tid * SCE;
    #pragma unroll
    for (int k = 0; k < SCE; ++k) {
        int i = base + k;
        if (i < n) off[i] += addv;
    }
}

// atomic-free CSR fill: col only (weights folded into u = dinv * x)
__global__ void fill_kernel(const int* __restrict__ row, const int* __restrict__ col,
                            const int* __restrict__ off, const int* __restrict__ slot,
                            int* __restrict__ csr_col, int E) {
    int e = blockIdx.x * blockDim.x + threadIdx.x;
    if (e < E) csr_col[off[row[e]] + slot[e]] = col[e];
}

// fused: G = winner>=0 ? Y[winner] : Z ; u0 = fp16(dinv * G)
__global__ void prep_kernel(const float4* __restrict__ Z4, const float4* __restrict__ Y4,
                            const int* __restrict__ winner, const float* __restrict__ dinv,
                            float4* __restrict__ G4, uint2* __restrict__ u0, int N) {
    int t = blockIdx.x * blockDim.x + threadIdx.x;
    if (t >= N * CH) return;
    int r = t / CH, q = t - r * CH;
    int w = winner[r];
    float4 g = (w >= 0) ? Y4[(size_t)w * CH + q] : Z4[t];
    G4[t] = g;
    float d = dinv[r];
    __half2 h0 = __floats2half2_rn(d * g.x, d * g.y);
    __half2 h1 = __floats2half2_rn(d * g.z, d * g.w);
    u0[t] = make_uint2(__builtin_bit_cast(unsigned int, h0),
                       __builtin_bit_cast(unsigned int, h1));
}

// --- diffusion step ------------------------------------------------------
// S_r = sum_{c in N(r)} u[c];  u_new = lam*dinv^2*S + 0.1*u0  (steps 0..8)
//                              x_out = lam*dinv  *S + 0.1*G   (final step)
// 12 lanes per row, each owns 4 fp16 features (8B gather/lane -> 96B/row).
template<bool LAST>
__global__ void diffuse_kernel(const uint2* __restrict__ up, const uint2* __restrict__ u0,
                               const float* __restrict__ dinv, const float4* __restrict__ G4,
                               const int* __restrict__ off, const int* __restrict__ cols,
                               uint2* __restrict__ uout, float4* __restrict__ xout, int N) {
    int t = blockIdx.x * blockDim.x + threadIdx.x;
    if (t >= N * CH) return;
    int r = t / CH, q = t - r * CH;
    int j0 = off[r], j1 = off[r + 1];
    float ax = 0.f, ay = 0.f, az = 0.f, aw = 0.f;
    int c = (j0 < j1) ? cols[j0] : 0;
    for (int j = j0; j < j1; ++j) {
        int cn = (j + 1 < j1) ? cols[j + 1] : 0;   // prefetch next col
        uint2 v = up[(size_t)c * CH + q];
        float2 f0 = __half22float2(__builtin_bit_cast(__half2, v.x));
        float2 f1 = __half22float2(__builtin_bit_cast(__half2, v.y));
        ax += f0.x; ay += f0.y; az += f1.x; aw += f1.y;
        c = cn;
    }
    float d = dinv[r];
    if (LAST) {
        float4 g = G4[t];
        float4 o;
        float s = LAM * d;
        o.x = fmaf(s, ax, OMLAM * g.x);
        o.y = fmaf(s, ay, OMLAM * g.y);
        o.z = fmaf(s, az, OMLAM * g.z);
        o.w = fmaf(s, aw, OMLAM * g.w);
        xout[t] = o;
    } else {
        float a = LAM * d * d;
        uint2 z = u0[t];
        float2 b0 = __half22float2(__builtin_bit_cast(__half2, z.x));
        float2 b1 = __half22float2(__builtin_bit_cast(__half2, z.y));
        __half2 h0 = __floats2half2_rn(fmaf(a, ax, OMLAM * b0.x),
                                       fmaf(a, ay, OMLAM * b0.y));
        __half2 h1 = __floats2half2_rn(fmaf(a, az, OMLAM * b1.x),
                                       fmaf(a, aw, OMLAM * b1.y));
        uout[t] = make_uint2(__builtin_bit_cast(unsigned int, h0),
                             __builtin_bit_cast(unsigned int, h1));
    }
}

// --- launch --------------------------------------------------------------

extern "C" void kernel_launch(void* const* d_in, const int* in_sizes, int n_in,
                              void* d_out, int out_size, void* d_ws, size_t ws_size,
                              hipStream_t stream) {
    const float* Z    = (const float*)d_in[0];
    const float* Y    = (const float*)d_in[1];
    const int*   mask = (const int*)d_in[2];
    const int*   ei   = (const int*)d_in[3];

    const int N = in_sizes[0] / FEAT;
    const int M = in_sizes[2];
    const int E = in_sizes[3] / 2;
    const int* row = ei;
    const int* col = ei + E;

    char* ws = (char*)d_ws;
    size_t pos = 0;
    auto alloc = [&](size_t bytes) -> void* {
        void* p = ws + pos;
        pos = (pos + bytes + 255) & ~(size_t)255;
        return p;
    };
    float* G      = (float*)alloc((size_t)N * FEAT * 4);
    uint2* u0     = (uint2*)alloc((size_t)N * CH * 8);
    uint2* ua     = (uint2*)alloc((size_t)N * CH * 8);
    uint2* ub     = (uint2*)alloc((size_t)N * CH * 8);
    int*   deg    = (int*)  alloc((size_t)N * 4);
    float* dinv   = (float*)alloc((size_t)N * 4);
    int*   cnt    = (int*)  alloc((size_t)N * 4);
    int*   off    = (int*)  alloc((size_t)(N + 1) * 4);
    int*   winner = (int*)  alloc((size_t)N * 4);
    int*   slot   = (int*)  alloc((size_t)E * 4);
    int*   csr    = (int*)  alloc((size_t)E * 4);
    int*   bsum   = (int*)  alloc((size_t)1024 * 4);

    hipMemsetAsync(deg,    0,    (size_t)N * 4, stream);
    hipMemsetAsync(cnt,    0,    (size_t)N * 4, stream);
    hipMemsetAsync(winner, 0xFF, (size_t)N * 4, stream);

    const int B = 256;
    count_kernel<<<2048, B, 0, stream>>>(row, col, deg, cnt, slot, mask, winner, E, M);
    dinv_kernel <<<(N + B - 1) / B, B, 0, stream>>>(deg, dinv, N);

    const int nt = N * CH;
    prep_kernel<<<(nt + B - 1) / B, B, 0, stream>>>((const float4*)Z, (const float4*)Y,
                                                    winner, dinv, (float4*)G, u0, N);

    const int scan_nb = (N + SCB * SCE - 1) / (SCB * SCE);
    scan_part <<<scan_nb, SCB, 0, stream>>>(cnt, off, bsum, N);
    scan_fixup<<<scan_nb, SCB, 0, stream>>>(off, bsum, scan_nb, N);

    fill_kernel<<<(E + B - 1) / B, B, 0, stream>>>(row, col, off, slot, csr, E);

    // steps 0..8 fp16 ping-pong, step 9 -> f32 d_out
    const uint2* src = u0;
    uint2* bufs[2] = { ua, ub };
    for (int it = 0; it < STEPS - 1; ++it) {
        uint2* dst = bufs[it & 1];
        diffuse_kernel<false><<<(nt + B - 1) / B, B, 0, stream>>>(
            src, u0, dinv, (const float4*)G, off, csr, dst, nullptr, N);
        src = dst;
    }
    diffuse_kernel<true><<<(nt + B - 1) / B, B, 0, stream>>>(
        src, u0, dinv, (const float4*)G, off, csr, nullptr, (float4*)d_out, N);
}